// Round 1
// baseline (186.347 us; speedup 1.0000x reference)
//
#include <hip/hip_runtime.h>

// PositionalEncoding: x[B,S,N,F] -> out[B,S,N,F+2]
// out[...,0:3] = x; out[...,3] = ||x_next - x||; out[...,4] = nan_to_num(acos(dot/(|x||x_next|)))
// x_next is the s+1 step (self-pair at s = S-1).
//
// B=64, S=4096, N=25, F=3. Memory-bound: 78.6 MB read + 131.1 MB write.

constexpr int Bc = 64, Sc = 4096, Nc = 25;
constexpr int TOTAL_G = Bc * Sc * Nc;  // 6,553,600 groups

__global__ __launch_bounds__(256) void pe_kernel(const float* __restrict__ x,
                                                 float* __restrict__ out) {
    int g = blockIdx.x * 256 + threadIdx.x;
    if (g >= TOTAL_G) return;

    int row = g / Nc;           // b*S + s   (magic-mul div by 25)
    int s = row & (Sc - 1);     // S is pow2
    int next_g = (s == Sc - 1) ? g : g + Nc;

    const float* xp = x + 3u * (unsigned)g;
    const float* yp = x + 3u * (unsigned)next_g;
    float x0 = xp[0], x1 = xp[1], x2 = xp[2];
    float y0 = yp[0], y1 = yp[1], y2 = yp[2];

    float d0 = y0 - x0, d1 = y1 - x1, d2 = y2 - x2;
    float dist = sqrtf(d0 * d0 + d1 * d1 + d2 * d2);

    float dot = x0 * y0 + x1 * y1 + x2 * y2;
    float nx = sqrtf(x0 * x0 + x1 * x1 + x2 * x2);
    float ny = sqrtf(y0 * y0 + y1 * y1 + y2 * y2);
    float ratio = dot / (nx * ny);
    float ang = acosf(ratio);          // NaN if |ratio| > 1 (rounding)
    if (isnan(ang)) ang = 0.0f;        // jnp.nan_to_num

    float* op = out + 5u * (unsigned)g;
    op[0] = x0;
    op[1] = x1;
    op[2] = x2;
    op[3] = dist;
    op[4] = ang;
}

extern "C" void kernel_launch(void* const* d_in, const int* in_sizes, int n_in,
                              void* d_out, int out_size, void* d_ws, size_t ws_size,
                              hipStream_t stream) {
    const float* x = (const float*)d_in[0];
    float* out = (float*)d_out;
    int grid = (TOTAL_G + 255) / 256;   // 25600 blocks
    pe_kernel<<<grid, 256, 0, stream>>>(x, out);
}